// Round 1
// baseline (117.973 us; speedup 1.0000x reference)
//
#include <hip/hip_runtime.h>
#include <math.h>

#define M_NODES 8192
#define K_PAR 8
#define C_CFG 256
#define N_LAYERS 8

__device__ __forceinline__ float fast_sigmoid(float x) {
    return 1.0f / (1.0f + __expf(-x));
}

// Root layer: marginal = sigmoid(logit)
__global__ __launch_bounds__(256) void root_kernel(const float* __restrict__ root_logits,
                                                   float* __restrict__ out) {
    int i = blockIdx.x * blockDim.x + threadIdx.x;
    if (i < M_NODES) out[i] = fast_sigmoid(root_logits[i]);
}

// One wave (64 lanes) per node. Lane `l` handles configs 4l .. 4l+3.
__global__ __launch_bounds__(256) void layer_kernel(const float* __restrict__ cpt,   // [M, C] this layer
                                                    const int*   __restrict__ par,   // [M, K] this layer
                                                    const float* __restrict__ prev,  // [M] previous marginals
                                                    float*       __restrict__ outm)  // [M] this layer's marginals
{
    const int wave = (blockIdx.x * blockDim.x + threadIdx.x) >> 6;
    const int lane = threadIdx.x & 63;
    if (wave >= M_NODES) return;
    const int m = wave;

    // lanes 0..7 gather parent marginals, then broadcast to all 64 lanes
    float pj = 0.0f;
    if (lane < K_PAR) {
        int idx = par[(size_t)m * K_PAR + lane];
        pj = prev[idx];
    }
    float p[K_PAR];
#pragma unroll
    for (int j = 0; j < K_PAR; ++j) p[j] = __shfl(pj, j, 64);

    // configs for this lane: c0 = 4*lane + t, t = 0..3.
    // bit for parent j (MSB-first): (c >> (7 - j)) & 1.
    // Top 6 bits (parents 0..5) are identical for the lane's 4 configs.
    const int c0 = lane << 2;
    float prefix = 1.0f;
#pragma unroll
    for (int j = 0; j < 6; ++j) {
        int bit = (c0 >> (7 - j)) & 1;
        prefix *= bit ? p[j] : (1.0f - p[j]);
    }
    const float p6 = p[6], p7 = p[7];
    const float q6 = 1.0f - p6, q7 = 1.0f - p7;
    const float w0 = prefix * (q6 * q7);  // t=0: bits (0,0)
    const float w1 = prefix * (q6 * p7);  // t=1: bits (0,1)
    const float w2 = prefix * (p6 * q7);  // t=2: bits (1,0)
    const float w3 = prefix * (p6 * p7);  // t=3: bits (1,1)

    // coalesced 16B load of this lane's 4 CPT logits
    const float4 q4 = *reinterpret_cast<const float4*>(cpt + (size_t)m * C_CFG + c0);

    float s = fast_sigmoid(q4.x) * w0
            + fast_sigmoid(q4.y) * w1
            + fast_sigmoid(q4.z) * w2
            + fast_sigmoid(q4.w) * w3;

    // wave-wide sum (64 lanes)
#pragma unroll
    for (int off = 32; off; off >>= 1) s += __shfl_xor(s, off, 64);

    if (lane == 0) outm[m] = s;
}

extern "C" void kernel_launch(void* const* d_in, const int* in_sizes, int n_in,
                              void* d_out, int out_size, void* d_ws, size_t ws_size,
                              hipStream_t stream) {
    const float* root_logits = (const float*)d_in[0];
    const float* cpt_logits  = (const float*)d_in[1];  // [N_LAYERS, M, C]
    const int*   parents     = (const int*)d_in[2];    // [N_LAYERS, M, K]
    float* out = (float*)d_out;                        // [(N_LAYERS+1) * M]

    // Root marginals -> out[0 : M]
    root_kernel<<<(M_NODES + 255) / 256, 256, 0, stream>>>(root_logits, out);

    // Each layer reads out[l*M : (l+1)*M], writes out[(l+1)*M : (l+2)*M]
    const int waves_per_block = 256 / 64;
    const int grid = (M_NODES + waves_per_block - 1) / waves_per_block;  // 2048 blocks
    for (int l = 0; l < N_LAYERS; ++l) {
        const float* cpt_l = cpt_logits + (size_t)l * M_NODES * C_CFG;
        const int*   par_l = parents + (size_t)l * M_NODES * K_PAR;
        const float* prev  = out + (size_t)l * M_NODES;
        float*       outm  = out + (size_t)(l + 1) * M_NODES;
        layer_kernel<<<grid, 256, 0, stream>>>(cpt_l, par_l, prev, outm);
    }
}